// Round 4
// baseline (223.789 us; speedup 1.0000x reference)
//
#include <hip/hip_runtime.h>
#include <math.h>
#include <float.h>

#define NB 4
#define NP 4096      // points (and vertices) per batch
#define NT 8192      // triangles
#define NS 128       // triangle splits
#define TCH (NT/NS)  // 64 triangles per chunk
#define GRID (NB*NS*4)  // 4 point-blocks of 1024 pts -> 2048 blocks
#define EPSD 1e-12
#define CINIT 0x7F7F7F7Fu   // memset(0x7F) pattern: +3.39e38 as float, init for counter too

typedef float f2 __attribute__((ext_vector_type(2)));

__device__ __forceinline__ float sigm(float x) { return 1.0f / (1.0f + expf(-x)); }

// Point-vs-triangle squared distance, 2 points packed per call (f2 lanes).
// Record fields: r0=[ax ay az abx] r1=[aby abz acx acy] r2=[acz aa am cc]
// r3=[raa rcc rbb rden] r4=[den bb k1 -]. dist = inside ? plane-projection
// : min over 3 clamped edge segments. inside = min3(vb,vc,va) > 0; strict >
// excludes degenerate triangles (den==0 -> vb=vc=va=0) and boundary
// strictness is harmless (di == m3 there by continuity).
__device__ __forceinline__ void tri_point(
    float4 r0, float4 r1, float4 r2, float4 r3, float4 r4,
    f2 px, f2 py, f2 pz, f2& mind)
{
  float abx = r0.w, aby = r1.x, abz = r1.y;
  float acx = r1.z, acy = r1.w, acz = r2.x;
  float aa = r2.y, am = r2.z, cc = r2.w;
  float raa = r3.x, rcc = r3.y, rbb = r3.z, rden = r3.w;
  float den = r4.x, bb = r4.y, k1 = r4.z;

  f2 apx = px - r0.x, apy = py - r0.y, apz = pz - r0.z;
  f2 d1   = apx * abx + apy * aby + apz * abz;
  f2 d2   = apx * acx + apy * acy + apz * acz;
  f2 apap = apx * apx + apy * apy + apz * apz;

  f2 vb = d1 * cc - d2 * am;
  f2 vc = d2 * aa - d1 * am;
  f2 va = den - vb - vc;
  f2 di = apap - (vb * d1 + vc * d2) * rden;

  f2 t2  = d1 + d1;
  f2 uab = d1 * raa;
  f2 tab; tab.x = fminf(fmaxf(uab.x, 0.0f), 1.0f);   // v_med3
          tab.y = fminf(fmaxf(uab.y, 0.0f), 1.0f);
  f2 dAB = apap + tab * (tab * aa - t2);

  f2 t4  = d2 + d2;
  f2 uac = d2 * rcc;
  f2 tac; tac.x = fminf(fmaxf(uac.x, 0.0f), 1.0f);
          tac.y = fminf(fmaxf(uac.y, 0.0f), 1.0f);
  f2 dAC = apap + tac * (tac * cc - t4);

  f2 e   = d2 - d1 + k1;
  f2 ubc = e * rbb;
  f2 tbc; tbc.x = fminf(fmaxf(ubc.x, 0.0f), 1.0f);
          tbc.y = fminf(fmaxf(ubc.y, 0.0f), 1.0f);
  f2 distB = apap - t2 + aa;
  f2 e2 = e + e;
  f2 dBC = distB + tbc * (tbc * bb - e2);

  float m3x = fminf(fminf(dAB.x, dAC.x), dBC.x);     // v_min3
  float m3y = fminf(fminf(dAB.y, dAC.y), dBC.y);
  float sx  = fminf(fminf(vb.x, vc.x), va.x);        // v_min3
  float sy  = fminf(fminf(vb.y, vc.y), va.y);
  float dx = (sx > 0.0f) ? di.x : m3x;
  float dy = (sy > 0.0f) ? di.y : m3y;
  mind.x = fminf(mind.x, dx);
  mind.y = fminf(mind.y, dy);
}

// Single fused kernel: per-block LDS triangle prep -> 4-points/thread distance
// loop -> atomicMin into part2 -> last block does masked mean + final scalar.
__global__ __launch_bounds__(256) void mega_kernel(
    const float* __restrict__ verts, const float* __restrict__ pc,
    const int* __restrict__ faces, unsigned int* __restrict__ part2,
    unsigned int* __restrict__ counter, float* __restrict__ out)
{
  __shared__ float4 rec[TCH][5];
  __shared__ unsigned int is_last;
  __shared__ float red[8];

  int bid  = blockIdx.x;
  int pblk = bid & 3;
  int s    = (bid >> 2) & (NS - 1);
  int b    = bid >> 9;
  int tid  = threadIdx.x;

  // ---- stage 1: prep this (b,s)'s 64 triangle records into LDS ----
  if (tid < TCH) {
    int t = s * TCH + tid;
    int f0 = faces[3 * t + 0], f1 = faces[3 * t + 1], f2i = faces[3 * t + 2];
    const float* vv = verts + (size_t)b * 3 * NP;
    float ax = sigm(vv[f0]),  ay = sigm(vv[NP + f0]),  az = sigm(vv[2 * NP + f0]);
    float bx = sigm(vv[f1]),  by = sigm(vv[NP + f1]),  bz = sigm(vv[2 * NP + f1]);
    float cx = sigm(vv[f2i]), cy = sigm(vv[NP + f2i]), cz = sigm(vv[2 * NP + f2i]);
    float abx = bx - ax, aby = by - ay, abz = bz - az;
    float acx = cx - ax, acy = cy - ay, acz = cz - az;
    double aa = (double)abx * abx + (double)aby * aby + (double)abz * abz;
    double am = (double)abx * acx + (double)aby * acy + (double)abz * acz;
    double cc = (double)acx * acx + (double)acy * acy + (double)acz * acz;
    double den = aa * cc - am * am;   // Gram det; exactly 0 iff degenerate
    double bb  = aa - 2.0 * am + cc;  // |bc|^2
    float raa  = (fabs(aa)  < EPSD) ? 1.0f : (float)(1.0 / aa);
    float rcc  = (fabs(cc)  < EPSD) ? 1.0f : (float)(1.0 / cc);
    float rbb  = (fabs(bb)  < EPSD) ? 1.0f : (float)(1.0 / bb);
    float rden = (fabs(den) < EPSD) ? 0.0f : (float)(1.0 / den);
    rec[tid][0] = make_float4(ax, ay, az, abx);
    rec[tid][1] = make_float4(aby, abz, acx, acy);
    rec[tid][2] = make_float4(acz, (float)aa, (float)am, (float)cc);
    rec[tid][3] = make_float4(raa, rcc, rbb, rden);
    rec[tid][4] = make_float4((float)den, (float)bb, (float)(aa - am), 0.0f);
  }
  __syncthreads();

  // ---- stage 2: 4 points/thread (two f2 chains) over 64 triangles ----
  int p0 = pblk * 1024 + tid;   // points p0, +256, +512, +768
  const float* pp = pc + ((size_t)b * NP + p0) * 3;
  f2 pxA, pyA, pzA, pxB, pyB, pzB;
  pxA.x = pp[0];    pyA.x = pp[1];    pzA.x = pp[2];
  pxA.y = pp[768];  pyA.y = pp[769];  pzA.y = pp[770];
  pxB.x = pp[1536]; pyB.x = pp[1537]; pzB.x = pp[1538];
  pxB.y = pp[2304]; pyB.y = pp[2305]; pzB.y = pp[2306];
  f2 mindA, mindB;
  mindA.x = mindA.y = mindB.x = mindB.y = 3.0e38f;

  #pragma unroll 2
  for (int t = 0; t < TCH; ++t) {
    float4 r0 = rec[t][0], r1 = rec[t][1], r2 = rec[t][2],
           r3 = rec[t][3], r4 = rec[t][4];
    tri_point(r0, r1, r2, r3, r4, pxA, pyA, pzA, mindA);
    tri_point(r0, r1, r2, r3, r4, pxB, pyB, pzB, mindB);
  }

  // ---- stage 3: cross-block per-point min via uint atomicMin ----
  unsigned int* dst = part2 + b * NP + p0;
  atomicMin(dst,       __float_as_uint(fmaxf(mindA.x, 0.0f)));
  atomicMin(dst + 256, __float_as_uint(fmaxf(mindA.y, 0.0f)));
  atomicMin(dst + 512, __float_as_uint(fmaxf(mindB.x, 0.0f)));
  atomicMin(dst + 768, __float_as_uint(fmaxf(mindB.y, 0.0f)));

  // ---- stage 4: last block finalizes ----
  __threadfence();   // release our mins before signaling
  if (tid == 0) {
    unsigned int old = atomicAdd(counter, 1u);
    is_last = (old == CINIT + (unsigned)GRID - 1u) ? 1u : 0u;
  }
  __syncthreads();
  if (is_last) {
    __threadfence();   // acquire all blocks' mins
    float loss = 0.0f;
    for (int bb = 0; bb < NB; ++bb) {
      float sdm = 0.0f, sm = 0.0f;
      for (int p = tid; p < NP; p += 256) {
        unsigned int u = __hip_atomic_load(&part2[bb * NP + p],
                                           __ATOMIC_RELAXED, __HIP_MEMORY_SCOPE_AGENT);
        float m = __uint_as_float(u);
        const float* q = pc + ((size_t)bb * NP + p) * 3;
        bool nz = (q[0] != 0.0f) | (q[1] != 0.0f) | (q[2] != 0.0f);
        if (nz) { sdm += m; sm += 1.0f; }
      }
      for (int off = 32; off > 0; off >>= 1) {
        sdm += __shfl_down(sdm, off, 64);
        sm  += __shfl_down(sm,  off, 64);
      }
      int wv = tid >> 6, ln = tid & 63;
      if (ln == 0) { red[wv] = sdm; red[4 + wv] = sm; }
      __syncthreads();
      if (tid == 0)
        loss += (red[0] + red[1] + red[2] + red[3]) /
                fmaxf(red[4] + red[5] + red[6] + red[7], 1.0f);
      __syncthreads();
    }
    if (tid == 0) out[0] = 0.25f * loss;
  }
}

extern "C" void kernel_launch(void* const* d_in, const int* in_sizes, int n_in,
                              void* d_out, int out_size, void* d_ws, size_t ws_size,
                              hipStream_t stream) {
  const float* verts = (const float*)d_in[0];   // (4,3,16,16,16) f32
  const float* pc    = (const float*)d_in[1];   // (4,4096,3) f32
  const int*   faces = (const int*)d_in[2];     // (8192,3) i32
  float* out = (float*)d_out;

  unsigned int* part2   = (unsigned int*)d_ws;        // NB*NP uints (64 KB)
  unsigned int* counter = part2 + NB * NP;            // 1 uint

  // Init part2 to +3.39e38 bit pattern and counter to CINIT in one fill.
  hipMemsetAsync(d_ws, 0x7F, (size_t)NB * NP * 4 + 4, stream);
  mega_kernel<<<GRID, 256, 0, stream>>>(verts, pc, faces, part2, counter, out);
}